// Round 17
// baseline (29.222 us; speedup 1.0000x reference)
//
#include <hip/hip_runtime.h>
#include <hip/hip_bf16.h>
#include <hip/hip_cooperative_groups.h>
#include <float.h>

namespace cg = cooperative_groups;

// ChamferLoss: preds [B,N,3] f32, gts [B,N,3] f32 -> scalar f32
// R17: R16 coop shell + R11 prepped 8B fragments. The loop is VALU-bound
// (R16 profile: MFMA-busy 6.5us vs VALU ~12us at effective ~1.15GHz clock);
// prepping {x,y,z,||t||^2} as f16x4 in a prep dispatch removes the ~10
// cvt/norm/pack VALU-ops per body -> body VALU ~= 18 (16 min3 merge floor).
// 2 dispatches: prep + coop(tile + grid.sync + reduce).

#define BLK  256

typedef _Float16 f16x8 __attribute__((ext_vector_type(8)));
typedef _Float16 f16x4 __attribute__((ext_vector_type(4)));
typedef float    f32x16 __attribute__((ext_vector_type(16)));
typedef float    f32x2 __attribute__((ext_vector_type(2)));
typedef float    f32x4 __attribute__((ext_vector_type(4)));

__device__ __forceinline__ unsigned int enc_f32(float f) {
    unsigned int u = __float_as_uint(f);
    return (u & 0x80000000u) ? ~u : (u | 0x80000000u);
}
__device__ __forceinline__ float dec_f32(unsigned int k) {
    return __uint_as_float((k & 0x80000000u) ? (k & 0x7FFFFFFFu) : ~k);
}

#define MFMA16(A, B, C) __builtin_amdgcn_mfma_f32_32x32x16_f16((A), (B), (C), 0, 0, 0)

// ---------------- prep: pack per-target fragment {x,y,z,||t||^2} ----------------
__global__ __launch_bounds__(BLK) void chamfer_prep(
    const float* __restrict__ preds, const float* __restrict__ gts,
    uint2* __restrict__ frag, int N) {
    int gid = blockIdx.x * BLK + threadIdx.x;     // [0, 2*4*N)
    int dir = gid / (4 * N);
    int rem = gid - dir * 4 * N;
    int b = rem / N, i = rem - b * N;
    const float* src = (dir == 0) ? gts : preds;  // dir0: queries=preds
    const float* p = src + ((size_t)b * N + i) * 3;
    float x = p[0], y = p[1], z = p[2];
    _Float16 hx = (_Float16)x, hy = (_Float16)y, hz = (_Float16)z;
    float tn = x * x + y * y + z * z;
    f16x4 f;
    f[0] = hx; f[1] = hy; f[2] = hz; f[3] = (_Float16)tn;
    frag[gid] = __builtin_bit_cast(uint2, f);
}

// ---------------- shared hot loop (noinline: isolated codegen) ----------------
// Wave processes N/4 targets (prepped fragments) for 64 queries (2 strips).
__device__ __noinline__ float2 chamfer_tile(
    const float* __restrict__ Q, const uint2* __restrict__ F,
    int N, int wave, int lane, int qb) {

    const int col = lane & 31;

    // B fragments (queries): k0-2 = -2q, k3 = 1, k4-7 = 0; lanes>=32 -> 0
    f16x8 bf0, bf1;
    {
        const _Float16 c0 = (_Float16)0.f, c1 = (_Float16)1.f, cm2 = (_Float16)(-2.f);
        int q0 = qb + col, q1 = qb + 32 + col;
        float x0 = Q[q0*3], y0 = Q[q0*3+1], z0 = Q[q0*3+2];
        float x1 = Q[q1*3], y1 = Q[q1*3+1], z1 = Q[q1*3+2];
        bf0[0] = (_Float16)x0 * cm2; bf0[1] = (_Float16)y0 * cm2; bf0[2] = (_Float16)z0 * cm2;
        bf0[3] = c1; bf0[4] = c0; bf0[5] = c0; bf0[6] = c0; bf0[7] = c0;
        bf1[0] = (_Float16)x1 * cm2; bf1[1] = (_Float16)y1 * cm2; bf1[2] = (_Float16)z1 * cm2;
        bf1[3] = c1; bf1[4] = c0; bf1[5] = c0; bf1[6] = c0; bf1[7] = c0;
        if (lane >= 32) {
            #pragma unroll
            for (int j = 0; j < 8; ++j) { bf0[j] = c0; bf1[j] = c0; }
        }
    }

    f32x16 cz;
    float rm0[8], rm1[8];
    #pragma unroll
    for (int j = 0; j < 16; ++j) cz[j] = 0.f;
    #pragma unroll
    for (int j = 0; j < 8; ++j) { rm0[j] = FLT_MAX; rm1[j] = FLT_MAX; }

    // 8 bodies (256 targets) per iteration, depth-8 fragment prefetch.
    // Lanes>=32 feed k=8..15 (B zero) -> alias to tile frag 0.
    const int NIT = N >> 10;                       // (N/4)/256
    const uint2* p = F + (size_t)wave * (N >> 2) + ((lane < 32) ? col : 0);

    uint2 f0 = p[0],   f1 = p[32],  f2 = p[64],  f3 = p[96];
    uint2 f4 = p[128], f5 = p[160], f6 = p[192], f7 = p[224];

#define BODY_T(FR, OFF)                                                 \
    {                                                                   \
        f16x4 alo = __builtin_bit_cast(f16x4, FR);                      \
        f16x8 a;                                                        \
        a[0] = alo[0]; a[1] = alo[1]; a[2] = alo[2]; a[3] = alo[3];     \
        a[4] = (_Float16)0.f; a[5] = (_Float16)0.f;                     \
        a[6] = (_Float16)0.f; a[7] = (_Float16)0.f;                     \
        f32x16 r0 = MFMA16(a, bf0, cz);                                 \
        f32x16 r1 = MFMA16(a, bf1, cz);                                 \
        _Pragma("unroll")                                               \
        for (int j = 0; j < 8; ++j) {                                   \
            rm0[j] = fminf(fminf(r0[2*j], r0[2*j+1]), rm0[j]);          \
            rm1[j] = fminf(fminf(r1[2*j], r1[2*j+1]), rm1[j]);          \
        }                                                               \
        FR = p[OFF];                                                    \
    }

    for (int it = 0; it < NIT; ++it) {
        BODY_T(f0, 256)
        BODY_T(f1, 288)
        BODY_T(f2, 320)
        BODY_T(f3, 352)
        BODY_T(f4, 384)
        BODY_T(f5, 416)
        BODY_T(f6, 448)
        BODY_T(f7, 480)
        p += 256;
    }
#undef BODY_T

    float m0 = rm0[0], m1 = rm1[0];
    #pragma unroll
    for (int j = 1; j < 8; ++j) { m0 = fminf(m0, rm0[j]); m1 = fminf(m1, rm1[j]); }
    return make_float2(m0, m1);
}

// ---------------- single-dispatch cooperative kernel ----------------
__global__ __launch_bounds__(BLK, 4) void chamfer_coop(
    const float* __restrict__ preds, const float* __restrict__ gts,
    const uint2* __restrict__ frag, float* __restrict__ partials,
    float* __restrict__ out, int N, int out_size) {

    const int dir  = blockIdx.z;
    const int b    = blockIdx.y;
    const int tid  = threadIdx.x;
    const int wave = tid >> 6;
    const int lane = tid & 63;
    const int qb   = blockIdx.x * 64;

    const float* Q = ((dir == 0) ? preds : gts) + (size_t)b * N * 3;
    const uint2* F = frag + ((size_t)dir * 4 + b) * N;

    float2 mm = chamfer_tile(Q, F, N, wave, lane, qb);

    __shared__ float lds[4][2][64];
    lds[wave][0][lane] = mm.x;
    lds[wave][1][lane] = mm.y;
    __syncthreads();

    if (tid < 64) {
        int s = tid >> 5, c = tid & 31;
        float m = FLT_MAX;
        #pragma unroll
        for (int w = 0; w < 4; ++w)
            m = fminf(m, fminf(lds[w][s][c], lds[w][s][c + 32]));
        int q = qb + s * 32 + c;
        float x = Q[q*3], y = Q[q*3+1], z = Q[q*3+2];
        float xr = (float)(_Float16)x, yr = (float)(_Float16)y, zr = (float)(_Float16)z;
        float val = m + (xr * xr + yr * yr + zr * zr);
        #pragma unroll
        for (int off = 32; off > 0; off >>= 1)
            val += __shfl_down(val, off, 64);
        if (tid == 0) {
            int flat = blockIdx.x + gridDim.x * (blockIdx.y + 4 * blockIdx.z);
            partials[flat] = val;
        }
    }
    __threadfence();
    cg::this_grid().sync();

    if (blockIdx.x == 0 && blockIdx.y == 0 && blockIdx.z == 0) {
        int nb = gridDim.x * gridDim.y * gridDim.z;
        float s = 0.f;
        for (int i = tid; i < nb; i += BLK) s += partials[i];
        __shared__ float psum[BLK / 64];
        #pragma unroll
        for (int off = 32; off > 0; off >>= 1) s += __shfl_down(s, off, 64);
        if ((tid & 63) == 0) psum[tid >> 6] = s;
        __syncthreads();
        if (tid == 0) {
            float t = 0.f;
            #pragma unroll
            for (int w = 0; w < BLK / 64; ++w) t += psum[w];
            out[0] = t;
        }
        for (int i = 1 + tid; i < out_size; i += BLK) out[i] = 0.f;
    }
}

// ---------------- fallback: frag-based two-dispatch path ----------------
__global__ __launch_bounds__(BLK, 4) void chamfer_mfma(
    const float* __restrict__ preds, const float* __restrict__ gts,
    const uint2* __restrict__ frag, float* __restrict__ partials, int N) {

    const int dir  = blockIdx.z;
    const int b    = blockIdx.y;
    const int tid  = threadIdx.x;
    const int wave = tid >> 6;
    const int lane = tid & 63;
    const int qb   = blockIdx.x * 64;

    const float* Q = ((dir == 0) ? preds : gts) + (size_t)b * N * 3;
    const uint2* F = frag + ((size_t)dir * 4 + b) * N;

    float2 mm = chamfer_tile(Q, F, N, wave, lane, qb);

    __shared__ float lds[4][2][64];
    lds[wave][0][lane] = mm.x;
    lds[wave][1][lane] = mm.y;
    __syncthreads();

    if (tid < 64) {
        int s = tid >> 5, c = tid & 31;
        float m = FLT_MAX;
        #pragma unroll
        for (int w = 0; w < 4; ++w)
            m = fminf(m, fminf(lds[w][s][c], lds[w][s][c + 32]));
        int q = qb + s * 32 + c;
        float x = Q[q*3], y = Q[q*3+1], z = Q[q*3+2];
        float xr = (float)(_Float16)x, yr = (float)(_Float16)y, zr = (float)(_Float16)z;
        float val = m + (xr * xr + yr * yr + zr * zr);
        #pragma unroll
        for (int off = 32; off > 0; off >>= 1)
            val += __shfl_down(val, off, 64);
        if (tid == 0) {
            int flat = blockIdx.x + gridDim.x * (blockIdx.y + 4 * blockIdx.z);
            partials[flat] = val;
        }
    }
}

__global__ __launch_bounds__(BLK) void chamfer_reduce(
    const float* __restrict__ partials, float* __restrict__ out,
    int nparts, int out_size) {
    const int tid = threadIdx.x;
    float s = 0.f;
    for (int i = tid; i < nparts; i += BLK) s += partials[i];
    __shared__ float psum[BLK / 64];
    #pragma unroll
    for (int off = 32; off > 0; off >>= 1) s += __shfl_down(s, off, 64);
    if ((tid & 63) == 0) psum[tid >> 6] = s;
    __syncthreads();
    if (tid == 0) {
        float t = 0.f;
        #pragma unroll
        for (int w = 0; w < BLK / 64; ++w) t += psum[w];
        out[0] = t;
    }
    for (int i = 1 + tid; i < out_size; i += BLK) out[i] = 0.f;
}

// ---------------- last-resort fallback (R5 VALU version) ----------------
#define SEG  32
#define Q    8

__device__ __forceinline__ float min3f(float a, float b, float c) {
    float r;
    asm("v_min3_f32 %0, %1, %2, %3" : "=v"(r) : "v"(a), "v"(b), "v"(c));
    return r;
}
__device__ __forceinline__ f32x2 pk_fma(f32x2 a, f32x2 b, f32x2 c) {
    f32x2 d;
    asm("v_pk_fma_f32 %0, %1, %2, %3" : "=v"(d) : "v"(a), "v"(b), "v"(c));
    return d;
}
__device__ __forceinline__ f32x2 pk_mul(f32x2 a, f32x2 b) {
    f32x2 d;
    asm("v_pk_mul_f32 %0, %1, %2" : "=v"(d) : "v"(a), "v"(b));
    return d;
}

__global__ __launch_bounds__(BLK, 4) void chamfer_min_kernel(
    const float* __restrict__ preds, const float* __restrict__ gts,
    unsigned int* __restrict__ keys, int N) {
    const int seg = blockIdx.z % SEG;
    const int dir = blockIdx.z / SEG;
    const int b   = blockIdx.y;
    const int tid = threadIdx.x;
    const int TT  = N / SEG;
    const float* Aq = dir == 0 ? preds : gts;
    const float* Bt = dir == 0 ? gts   : preds;
    const float* Ab = Aq + (size_t)b * N * 3;
    const float* Bb = Bt + (size_t)b * N * 3;
    __shared__ f32x2 shx[256], shy[256], shz[256];
    const int qbase = blockIdx.x * (BLK * Q);
    f32x2 a2x[Q], a2y[Q], a2z[Q];
    float an[Q]; bool vq[Q];
    #pragma unroll
    for (int q = 0; q < Q; ++q) {
        int idx = qbase + q * BLK + tid;
        vq[q] = idx < N;
        int ci = vq[q] ? idx : 0;
        float ax = Ab[ci*3], ay = Ab[ci*3+1], az = Ab[ci*3+2];
        a2x[q] = f32x2{-2.f*ax, -2.f*ax};
        a2y[q] = f32x2{-2.f*ay, -2.f*ay};
        a2z[q] = f32x2{-2.f*az, -2.f*az};
        an[q]  = ax*ax + ay*ay + az*az;
    }
    for (int p = tid; p < (TT >> 1); p += BLK) {
        int j0 = seg * TT + 2 * p;
        const f32x2* src = (const f32x2*)(Bb + (size_t)j0 * 3);
        f32x2 v01 = src[0], v23 = src[1], v45 = src[2];
        shx[p] = f32x2{v01.x, v23.y};
        shy[p] = f32x2{v01.y, v45.x};
        shz[p] = f32x2{v23.x, v45.y};
    }
    __syncthreads();
    float m[Q];
    #pragma unroll
    for (int q = 0; q < Q; ++q) m[q] = FLT_MAX;
    const f32x4* X4 = (const f32x4*)shx;
    const f32x4* Y4 = (const f32x4*)shy;
    const f32x4* Z4 = (const f32x4*)shz;
    const int KITER = TT >> 2;
    #pragma unroll 2
    for (int k = 0; k < KITER; ++k) {
        f32x4 X = X4[k], Y = Y4[k], Z = Z4[k];
        f32x2 w01 = pk_fma(Z.lo, Z.lo, pk_fma(Y.lo, Y.lo, pk_mul(X.lo, X.lo)));
        f32x2 w23 = pk_fma(Z.hi, Z.hi, pk_fma(Y.hi, Y.hi, pk_mul(X.hi, X.hi)));
        #pragma unroll
        for (int q = 0; q < Q; ++q) {
            f32x2 d0 = pk_fma(a2x[q], X.lo, pk_fma(a2y[q], Y.lo, pk_fma(a2z[q], Z.lo, w01)));
            f32x2 d1 = pk_fma(a2x[q], X.hi, pk_fma(a2y[q], Y.hi, pk_fma(a2z[q], Z.hi, w23)));
            m[q] = min3f(d0.x, d0.y, m[q]);
            m[q] = min3f(d1.x, d1.y, m[q]);
        }
    }
    #pragma unroll
    for (int q = 0; q < Q; ++q) {
        if (vq[q]) {
            int idx = qbase + q * BLK + tid;
            atomicMin(keys + ((size_t)(dir*4 + b) * N + idx), enc_f32(m[q] + an[q]));
        }
    }
}

__global__ __launch_bounds__(BLK) void chamfer_sum_kernel(
    const unsigned int* __restrict__ keys, float* __restrict__ out, int M) {
    __shared__ float psum[BLK / 64];
    int gid = blockIdx.x * BLK + threadIdx.x;
    int stride = gridDim.x * BLK;
    float s = 0.f;
    for (int i = gid; i < M; i += stride) s += dec_f32(keys[i]);
    for (int off = 32; off > 0; off >>= 1) s += __shfl_down(s, off, 64);
    if ((threadIdx.x & 63) == 0) psum[threadIdx.x >> 6] = s;
    __syncthreads();
    if (threadIdx.x == 0) {
        float t = 0.f;
        for (int w = 0; w < BLK / 64; ++w) t += psum[w];
        atomicAdd(out, t);
    }
}

extern "C" void kernel_launch(void* const* d_in, const int* in_sizes, int n_in,
                              void* d_out, int out_size, void* d_ws, size_t ws_size,
                              hipStream_t stream) {
    const float* preds = (const float*)d_in[0];
    const float* gts   = (const float*)d_in[1];
    float* out = (float*)d_out;

    const int B = 4, D = 3;
    const int N = in_sizes[0] / (B * D);   // 8192

    // ws layout: [frag: 2*B*N uint2][4KB pad][partials: nb floats]
    const size_t frag_bytes = (size_t)2 * B * N * sizeof(uint2);
    const int    nb         = (N / 64) * B * 2;    // 1024
    const size_t part_off   = frag_bytes + 4096;
    const size_t need       = part_off + (size_t)nb * sizeof(float);

    if (ws_size >= need && (N % 1024) == 0) {
        uint2* frag = (uint2*)d_ws;
        float* partials = (float*)((char*)d_ws + part_off);
        int npts = 2 * B * N;
        chamfer_prep<<<npts / BLK, BLK, 0, stream>>>(preds, gts, frag, N);

        dim3 grid(N / 64, B, 2);
        bool launched = false;
        int occ = 0;
        hipError_t qrc = hipOccupancyMaxActiveBlocksPerMultiprocessor(
            &occ, reinterpret_cast<const void*>(chamfer_coop), BLK, 0);
        long long total_blocks = (long long)grid.x * grid.y * grid.z;
        if (qrc == hipSuccess && (long long)occ * 256 >= total_blocks) {
            int n_local = N, osz_local = out_size;
            void* args[] = {(void*)&preds, (void*)&gts, (void*)&frag,
                            (void*)&partials, (void*)&out,
                            (void*)&n_local, (void*)&osz_local};
            hipError_t rc = hipLaunchCooperativeKernel(
                reinterpret_cast<const void*>(chamfer_coop),
                grid, dim3(BLK), args, 0, stream);
            launched = (rc == hipSuccess);
        }
        if (!launched) {
            chamfer_mfma<<<grid, BLK, 0, stream>>>(preds, gts, frag, partials, N);
            chamfer_reduce<<<1, BLK, 0, stream>>>(partials, out, nb, out_size);
        }
    } else {
        hipMemsetAsync(out, 0, sizeof(float) * out_size, stream);
        const size_t keys_bytes = (size_t)2 * B * N * sizeof(unsigned int);
        unsigned int* keys = (unsigned int*)d_ws;
        hipMemsetAsync(keys, 0xFF, keys_bytes, stream);
        dim3 grid((N + BLK * Q - 1) / (BLK * Q), B, 2 * SEG);
        chamfer_min_kernel<<<grid, BLK, 0, stream>>>(preds, gts, keys, N);
        chamfer_sum_kernel<<<64, BLK, 0, stream>>>(keys, out, 2 * B * N);
    }
}

// Round 18
// 29.181 us; speedup vs baseline: 1.0014x; 1.0014x over previous
//
#include <hip/hip_runtime.h>
#include <hip/hip_bf16.h>
#include <hip/hip_cooperative_groups.h>
#include <float.h>

namespace cg = cooperative_groups;

// ChamferLoss: preds [B,N,3] f32, gts [B,N,3] f32 -> scalar f32
// R18: single coop dispatch with 3 phases: (0) grid-wide fragment prep
// ({x,y,z,||t||^2} f16x4, each target converted ONCE instead of 128x),
// grid.sync; (1) frag tile loop (noinline, R17-proven); (2) grid.sync +
// block-0 reduce. R17 showed the frag loop is lighter (VALUBusy 6.2->5.2%)
// but its separate prep dispatch cost more than the saving -- fusing prep
// as phase-0 keeps the saving without the dispatch.

#define BLK  256

typedef _Float16 f16x8 __attribute__((ext_vector_type(8)));
typedef _Float16 f16x4 __attribute__((ext_vector_type(4)));
typedef float    f32x16 __attribute__((ext_vector_type(16)));
typedef float    f32x2 __attribute__((ext_vector_type(2)));
typedef float    f32x4 __attribute__((ext_vector_type(4)));

__device__ __forceinline__ unsigned int enc_f32(float f) {
    unsigned int u = __float_as_uint(f);
    return (u & 0x80000000u) ? ~u : (u | 0x80000000u);
}
__device__ __forceinline__ float dec_f32(unsigned int k) {
    return __uint_as_float((k & 0x80000000u) ? (k & 0x7FFFFFFFu) : ~k);
}

#define MFMA16(A, B, C) __builtin_amdgcn_mfma_f32_32x32x16_f16((A), (B), (C), 0, 0, 0)

// ---------------- fragment prep (shared by kernel + phase-0) ----------------
__device__ __forceinline__ void prep_one(
    const float* __restrict__ preds, const float* __restrict__ gts,
    uint2* __restrict__ frag, int N, int gid) {
    int dir = gid / (4 * N);
    int rem = gid - dir * 4 * N;
    int b = rem / N, i = rem - b * N;
    const float* src = (dir == 0) ? gts : preds;  // dir0: queries=preds
    const float* p = src + ((size_t)b * N + i) * 3;
    float x = p[0], y = p[1], z = p[2];
    _Float16 hx = (_Float16)x, hy = (_Float16)y, hz = (_Float16)z;
    float tn = x * x + y * y + z * z;
    f16x4 f;
    f[0] = hx; f[1] = hy; f[2] = hz; f[3] = (_Float16)tn;
    frag[gid] = __builtin_bit_cast(uint2, f);
}

__global__ __launch_bounds__(BLK) void chamfer_prep(
    const float* __restrict__ preds, const float* __restrict__ gts,
    uint2* __restrict__ frag, int N) {
    int gid = blockIdx.x * BLK + threadIdx.x;
    prep_one(preds, gts, frag, N, gid);
}

// ---------------- shared hot loop (noinline: isolated codegen) ----------------
// Wave processes N/4 targets (prepped fragments) for 64 queries (2 strips).
__device__ __noinline__ float2 chamfer_tile(
    const float* __restrict__ Q, const uint2* __restrict__ F,
    int N, int wave, int lane, int qb) {

    const int col = lane & 31;

    // B fragments (queries): k0-2 = -2q, k3 = 1, k4-7 = 0; lanes>=32 -> 0
    f16x8 bf0, bf1;
    {
        const _Float16 c0 = (_Float16)0.f, c1 = (_Float16)1.f, cm2 = (_Float16)(-2.f);
        int q0 = qb + col, q1 = qb + 32 + col;
        float x0 = Q[q0*3], y0 = Q[q0*3+1], z0 = Q[q0*3+2];
        float x1 = Q[q1*3], y1 = Q[q1*3+1], z1 = Q[q1*3+2];
        bf0[0] = (_Float16)x0 * cm2; bf0[1] = (_Float16)y0 * cm2; bf0[2] = (_Float16)z0 * cm2;
        bf0[3] = c1; bf0[4] = c0; bf0[5] = c0; bf0[6] = c0; bf0[7] = c0;
        bf1[0] = (_Float16)x1 * cm2; bf1[1] = (_Float16)y1 * cm2; bf1[2] = (_Float16)z1 * cm2;
        bf1[3] = c1; bf1[4] = c0; bf1[5] = c0; bf1[6] = c0; bf1[7] = c0;
        if (lane >= 32) {
            #pragma unroll
            for (int j = 0; j < 8; ++j) { bf0[j] = c0; bf1[j] = c0; }
        }
    }

    f32x16 cz;
    float rm0[8], rm1[8];
    #pragma unroll
    for (int j = 0; j < 16; ++j) cz[j] = 0.f;
    #pragma unroll
    for (int j = 0; j < 8; ++j) { rm0[j] = FLT_MAX; rm1[j] = FLT_MAX; }

    // 8 bodies (256 targets) per iteration, depth-8 fragment prefetch.
    // Lanes>=32 feed k=8..15 (B zero) -> alias to tile frag 0.
    const int NIT = N >> 10;                       // (N/4)/256
    const uint2* p = F + (size_t)wave * (N >> 2) + ((lane < 32) ? col : 0);

    uint2 f0 = p[0],   f1 = p[32],  f2 = p[64],  f3 = p[96];
    uint2 f4 = p[128], f5 = p[160], f6 = p[192], f7 = p[224];

#define BODY_T(FR, OFF)                                                 \
    {                                                                   \
        f16x4 alo = __builtin_bit_cast(f16x4, FR);                      \
        f16x8 a;                                                        \
        a[0] = alo[0]; a[1] = alo[1]; a[2] = alo[2]; a[3] = alo[3];     \
        a[4] = (_Float16)0.f; a[5] = (_Float16)0.f;                     \
        a[6] = (_Float16)0.f; a[7] = (_Float16)0.f;                     \
        f32x16 r0 = MFMA16(a, bf0, cz);                                 \
        f32x16 r1 = MFMA16(a, bf1, cz);                                 \
        _Pragma("unroll")                                               \
        for (int j = 0; j < 8; ++j) {                                   \
            rm0[j] = fminf(fminf(r0[2*j], r0[2*j+1]), rm0[j]);          \
            rm1[j] = fminf(fminf(r1[2*j], r1[2*j+1]), rm1[j]);          \
        }                                                               \
        FR = p[OFF];                                                    \
    }

    for (int it = 0; it < NIT; ++it) {
        BODY_T(f0, 256)
        BODY_T(f1, 288)
        BODY_T(f2, 320)
        BODY_T(f3, 352)
        BODY_T(f4, 384)
        BODY_T(f5, 416)
        BODY_T(f6, 448)
        BODY_T(f7, 480)
        p += 256;
    }
#undef BODY_T

    float m0 = rm0[0], m1 = rm1[0];
    #pragma unroll
    for (int j = 1; j < 8; ++j) { m0 = fminf(m0, rm0[j]); m1 = fminf(m1, rm1[j]); }
    return make_float2(m0, m1);
}

// ---------------- single-dispatch cooperative kernel ----------------
__global__ __launch_bounds__(BLK, 4) void chamfer_coop(
    const float* __restrict__ preds, const float* __restrict__ gts,
    uint2* __restrict__ frag, float* __restrict__ partials,
    float* __restrict__ out, int N, int out_size) {

    const int dir  = blockIdx.z;
    const int b    = blockIdx.y;
    const int tid  = threadIdx.x;
    const int wave = tid >> 6;
    const int lane = tid & 63;
    const int qb   = blockIdx.x * 64;

    // ---- phase 0: grid-wide fragment prep (each target converted once) ----
    {
        int flat = blockIdx.x + gridDim.x * (blockIdx.y + 4 * blockIdx.z);
        int gid  = flat * BLK + tid;
        int npts = 8 * N;                          // 2*B*N
        if (gid < npts) prep_one(preds, gts, frag, N, gid);
    }
    __threadfence();
    cg::this_grid().sync();

    // ---- phase 1: tile loop on fragments ----
    const float* Q = ((dir == 0) ? preds : gts) + (size_t)b * N * 3;
    const uint2* F = frag + ((size_t)dir * 4 + b) * N;

    float2 mm = chamfer_tile(Q, F, N, wave, lane, qb);

    __shared__ float lds[4][2][64];
    lds[wave][0][lane] = mm.x;
    lds[wave][1][lane] = mm.y;
    __syncthreads();

    if (tid < 64) {
        int s = tid >> 5, c = tid & 31;
        float m = FLT_MAX;
        #pragma unroll
        for (int w = 0; w < 4; ++w)
            m = fminf(m, fminf(lds[w][s][c], lds[w][s][c + 32]));
        int q = qb + s * 32 + c;
        float x = Q[q*3], y = Q[q*3+1], z = Q[q*3+2];
        float xr = (float)(_Float16)x, yr = (float)(_Float16)y, zr = (float)(_Float16)z;
        float val = m + (xr * xr + yr * yr + zr * zr);
        #pragma unroll
        for (int off = 32; off > 0; off >>= 1)
            val += __shfl_down(val, off, 64);
        if (tid == 0) {
            int flat = blockIdx.x + gridDim.x * (blockIdx.y + 4 * blockIdx.z);
            partials[flat] = val;
        }
    }
    __threadfence();
    cg::this_grid().sync();

    // ---- phase 2: block 0 reduces in fixed order ----
    if (blockIdx.x == 0 && blockIdx.y == 0 && blockIdx.z == 0) {
        int nb = gridDim.x * gridDim.y * gridDim.z;
        float s = 0.f;
        for (int i = tid; i < nb; i += BLK) s += partials[i];
        __shared__ float psum[BLK / 64];
        #pragma unroll
        for (int off = 32; off > 0; off >>= 1) s += __shfl_down(s, off, 64);
        if ((tid & 63) == 0) psum[tid >> 6] = s;
        __syncthreads();
        if (tid == 0) {
            float t = 0.f;
            #pragma unroll
            for (int w = 0; w < BLK / 64; ++w) t += psum[w];
            out[0] = t;
        }
        for (int i = 1 + tid; i < out_size; i += BLK) out[i] = 0.f;
    }
}

// ---------------- fallback: frag-based two-dispatch path ----------------
__global__ __launch_bounds__(BLK, 4) void chamfer_mfma(
    const float* __restrict__ preds, const float* __restrict__ gts,
    const uint2* __restrict__ frag, float* __restrict__ partials, int N) {

    const int dir  = blockIdx.z;
    const int b    = blockIdx.y;
    const int tid  = threadIdx.x;
    const int wave = tid >> 6;
    const int lane = tid & 63;
    const int qb   = blockIdx.x * 64;

    const float* Q = ((dir == 0) ? preds : gts) + (size_t)b * N * 3;
    const uint2* F = frag + ((size_t)dir * 4 + b) * N;

    float2 mm = chamfer_tile(Q, F, N, wave, lane, qb);

    __shared__ float lds[4][2][64];
    lds[wave][0][lane] = mm.x;
    lds[wave][1][lane] = mm.y;
    __syncthreads();

    if (tid < 64) {
        int s = tid >> 5, c = tid & 31;
        float m = FLT_MAX;
        #pragma unroll
        for (int w = 0; w < 4; ++w)
            m = fminf(m, fminf(lds[w][s][c], lds[w][s][c + 32]));
        int q = qb + s * 32 + c;
        float x = Q[q*3], y = Q[q*3+1], z = Q[q*3+2];
        float xr = (float)(_Float16)x, yr = (float)(_Float16)y, zr = (float)(_Float16)z;
        float val = m + (xr * xr + yr * yr + zr * zr);
        #pragma unroll
        for (int off = 32; off > 0; off >>= 1)
            val += __shfl_down(val, off, 64);
        if (tid == 0) {
            int flat = blockIdx.x + gridDim.x * (blockIdx.y + 4 * blockIdx.z);
            partials[flat] = val;
        }
    }
}

__global__ __launch_bounds__(BLK) void chamfer_reduce(
    const float* __restrict__ partials, float* __restrict__ out,
    int nparts, int out_size) {
    const int tid = threadIdx.x;
    float s = 0.f;
    for (int i = tid; i < nparts; i += BLK) s += partials[i];
    __shared__ float psum[BLK / 64];
    #pragma unroll
    for (int off = 32; off > 0; off >>= 1) s += __shfl_down(s, off, 64);
    if ((tid & 63) == 0) psum[tid >> 6] = s;
    __syncthreads();
    if (tid == 0) {
        float t = 0.f;
        #pragma unroll
        for (int w = 0; w < BLK / 64; ++w) t += psum[w];
        out[0] = t;
    }
    for (int i = 1 + tid; i < out_size; i += BLK) out[i] = 0.f;
}

// ---------------- last-resort fallback (R5 VALU version) ----------------
#define SEG  32
#define Q    8

__device__ __forceinline__ float min3f(float a, float b, float c) {
    float r;
    asm("v_min3_f32 %0, %1, %2, %3" : "=v"(r) : "v"(a), "v"(b), "v"(c));
    return r;
}
__device__ __forceinline__ f32x2 pk_fma(f32x2 a, f32x2 b, f32x2 c) {
    f32x2 d;
    asm("v_pk_fma_f32 %0, %1, %2, %3" : "=v"(d) : "v"(a), "v"(b), "v"(c));
    return d;
}
__device__ __forceinline__ f32x2 pk_mul(f32x2 a, f32x2 b) {
    f32x2 d;
    asm("v_pk_mul_f32 %0, %1, %2" : "=v"(d) : "v"(a), "v"(b));
    return d;
}

__global__ __launch_bounds__(BLK, 4) void chamfer_min_kernel(
    const float* __restrict__ preds, const float* __restrict__ gts,
    unsigned int* __restrict__ keys, int N) {
    const int seg = blockIdx.z % SEG;
    const int dir = blockIdx.z / SEG;
    const int b   = blockIdx.y;
    const int tid = threadIdx.x;
    const int TT  = N / SEG;
    const float* Aq = dir == 0 ? preds : gts;
    const float* Bt = dir == 0 ? gts   : preds;
    const float* Ab = Aq + (size_t)b * N * 3;
    const float* Bb = Bt + (size_t)b * N * 3;
    __shared__ f32x2 shx[256], shy[256], shz[256];
    const int qbase = blockIdx.x * (BLK * Q);
    f32x2 a2x[Q], a2y[Q], a2z[Q];
    float an[Q]; bool vq[Q];
    #pragma unroll
    for (int q = 0; q < Q; ++q) {
        int idx = qbase + q * BLK + tid;
        vq[q] = idx < N;
        int ci = vq[q] ? idx : 0;
        float ax = Ab[ci*3], ay = Ab[ci*3+1], az = Ab[ci*3+2];
        a2x[q] = f32x2{-2.f*ax, -2.f*ax};
        a2y[q] = f32x2{-2.f*ay, -2.f*ay};
        a2z[q] = f32x2{-2.f*az, -2.f*az};
        an[q]  = ax*ax + ay*ay + az*az;
    }
    for (int p = tid; p < (TT >> 1); p += BLK) {
        int j0 = seg * TT + 2 * p;
        const f32x2* src = (const f32x2*)(Bb + (size_t)j0 * 3);
        f32x2 v01 = src[0], v23 = src[1], v45 = src[2];
        shx[p] = f32x2{v01.x, v23.y};
        shy[p] = f32x2{v01.y, v45.x};
        shz[p] = f32x2{v23.x, v45.y};
    }
    __syncthreads();
    float m[Q];
    #pragma unroll
    for (int q = 0; q < Q; ++q) m[q] = FLT_MAX;
    const f32x4* X4 = (const f32x4*)shx;
    const f32x4* Y4 = (const f32x4*)shy;
    const f32x4* Z4 = (const f32x4*)shz;
    const int KITER = TT >> 2;
    #pragma unroll 2
    for (int k = 0; k < KITER; ++k) {
        f32x4 X = X4[k], Y = Y4[k], Z = Z4[k];
        f32x2 w01 = pk_fma(Z.lo, Z.lo, pk_fma(Y.lo, Y.lo, pk_mul(X.lo, X.lo)));
        f32x2 w23 = pk_fma(Z.hi, Z.hi, pk_fma(Y.hi, Y.hi, pk_mul(X.hi, X.hi)));
        #pragma unroll
        for (int q = 0; q < Q; ++q) {
            f32x2 d0 = pk_fma(a2x[q], X.lo, pk_fma(a2y[q], Y.lo, pk_fma(a2z[q], Z.lo, w01)));
            f32x2 d1 = pk_fma(a2x[q], X.hi, pk_fma(a2y[q], Y.hi, pk_fma(a2z[q], Z.hi, w23)));
            m[q] = min3f(d0.x, d0.y, m[q]);
            m[q] = min3f(d1.x, d1.y, m[q]);
        }
    }
    #pragma unroll
    for (int q = 0; q < Q; ++q) {
        if (vq[q]) {
            int idx = qbase + q * BLK + tid;
            atomicMin(keys + ((size_t)(dir*4 + b) * N + idx), enc_f32(m[q] + an[q]));
        }
    }
}

__global__ __launch_bounds__(BLK) void chamfer_sum_kernel(
    const unsigned int* __restrict__ keys, float* __restrict__ out, int M) {
    __shared__ float psum[BLK / 64];
    int gid = blockIdx.x * BLK + threadIdx.x;
    int stride = gridDim.x * BLK;
    float s = 0.f;
    for (int i = gid; i < M; i += stride) s += dec_f32(keys[i]);
    for (int off = 32; off > 0; off >>= 1) s += __shfl_down(s, off, 64);
    if ((threadIdx.x & 63) == 0) psum[threadIdx.x >> 6] = s;
    __syncthreads();
    if (threadIdx.x == 0) {
        float t = 0.f;
        for (int w = 0; w < BLK / 64; ++w) t += psum[w];
        atomicAdd(out, t);
    }
}

extern "C" void kernel_launch(void* const* d_in, const int* in_sizes, int n_in,
                              void* d_out, int out_size, void* d_ws, size_t ws_size,
                              hipStream_t stream) {
    const float* preds = (const float*)d_in[0];
    const float* gts   = (const float*)d_in[1];
    float* out = (float*)d_out;

    const int B = 4, D = 3;
    const int N = in_sizes[0] / (B * D);   // 8192

    // ws layout: [frag: 2*B*N uint2][4KB pad][partials: nb floats]
    const size_t frag_bytes = (size_t)2 * B * N * sizeof(uint2);
    const int    nb         = (N / 64) * B * 2;    // 1024
    const size_t part_off   = frag_bytes + 4096;
    const size_t need       = part_off + (size_t)nb * sizeof(float);

    if (ws_size >= need && (N % 1024) == 0) {
        uint2* frag = (uint2*)d_ws;
        float* partials = (float*)((char*)d_ws + part_off);
        dim3 grid(N / 64, B, 2);

        // blocks x threads must cover 2*B*N prep items in phase 0
        long long total_blocks = (long long)grid.x * grid.y * grid.z;
        bool cover = total_blocks * BLK >= (long long)2 * B * N;

        bool launched = false;
        int occ = 0;
        hipError_t qrc = hipOccupancyMaxActiveBlocksPerMultiprocessor(
            &occ, reinterpret_cast<const void*>(chamfer_coop), BLK, 0);
        if (cover && qrc == hipSuccess && (long long)occ * 256 >= total_blocks) {
            int n_local = N, osz_local = out_size;
            void* args[] = {(void*)&preds, (void*)&gts, (void*)&frag,
                            (void*)&partials, (void*)&out,
                            (void*)&n_local, (void*)&osz_local};
            hipError_t rc = hipLaunchCooperativeKernel(
                reinterpret_cast<const void*>(chamfer_coop),
                grid, dim3(BLK), args, 0, stream);
            launched = (rc == hipSuccess);
        }
        if (!launched) {
            int npts = 2 * B * N;
            chamfer_prep<<<npts / BLK, BLK, 0, stream>>>(preds, gts, frag, N);
            chamfer_mfma<<<grid, BLK, 0, stream>>>(preds, gts, frag, partials, N);
            chamfer_reduce<<<1, BLK, 0, stream>>>(partials, out, nb, out_size);
        }
    } else {
        hipMemsetAsync(out, 0, sizeof(float) * out_size, stream);
        const size_t keys_bytes = (size_t)2 * B * N * sizeof(unsigned int);
        unsigned int* keys = (unsigned int*)d_ws;
        hipMemsetAsync(keys, 0xFF, keys_bytes, stream);
        dim3 grid((N + BLK * Q - 1) / (BLK * Q), B, 2 * SEG);
        chamfer_min_kernel<<<grid, BLK, 0, stream>>>(preds, gts, keys, N);
        chamfer_sum_kernel<<<64, BLK, 0, stream>>>(keys, out, 2 * B * N);
    }
}

// Round 21
// 25.051 us; speedup vs baseline: 1.1665x; 1.1649x over previous
//
#include <hip/hip_runtime.h>
#include <hip/hip_bf16.h>
#include <hip/hip_cooperative_groups.h>
#include <float.h>

namespace cg = cooperative_groups;

// ChamferLoss: preds [B,N,3] f32, gts [B,N,3] f32 -> scalar f32
// R21: champion restore (= R16, 25.2us, absmax 0.0). R20's cvt_pkrtz was
// numerically unsafe: RTZ biases every target norm downward and the bias
// sums coherently over 65K query minima (absmax 72 > 30.5). Scalar RNE
// conversion (compiler v_cvt_f16_f32) is required. Single cooperative
// dispatch: tile loop (noinline) -> partial store -> grid.sync -> block-0
// fixed-order reduce.

#define BLK  256

typedef _Float16 f16x8 __attribute__((ext_vector_type(8)));
typedef float    f32x16 __attribute__((ext_vector_type(16)));
typedef float    f32x2 __attribute__((ext_vector_type(2)));
typedef float    f32x4 __attribute__((ext_vector_type(4)));

__device__ __forceinline__ unsigned int enc_f32(float f) {
    unsigned int u = __float_as_uint(f);
    return (u & 0x80000000u) ? ~u : (u | 0x80000000u);
}
__device__ __forceinline__ float dec_f32(unsigned int k) {
    return __uint_as_float((k & 0x80000000u) ? (k & 0x7FFFFFFFu) : ~k);
}

#define MFMA16(A, B, C) __builtin_amdgcn_mfma_f32_32x32x16_f16((A), (B), (C), 0, 0, 0)

// ---------------- shared hot loop (noinline: isolated codegen) ----------------
// Wave processes N/4 targets for 64 queries (2 strips); returns (m0, m1).
__device__ __noinline__ float2 chamfer_tile(
    const float* __restrict__ Q, const float* __restrict__ T,
    int N, int wave, int lane, int qb) {

    const int col = lane & 31;

    // B fragments (queries): k0-2 = -2q, k3 = 1, k4-7 = 0; lanes>=32 -> 0
    f16x8 bf0, bf1;
    {
        const _Float16 c0 = (_Float16)0.f, c1 = (_Float16)1.f, cm2 = (_Float16)(-2.f);
        int q0 = qb + col, q1 = qb + 32 + col;
        float x0 = Q[q0*3], y0 = Q[q0*3+1], z0 = Q[q0*3+2];
        float x1 = Q[q1*3], y1 = Q[q1*3+1], z1 = Q[q1*3+2];
        bf0[0] = (_Float16)x0 * cm2; bf0[1] = (_Float16)y0 * cm2; bf0[2] = (_Float16)z0 * cm2;
        bf0[3] = c1; bf0[4] = c0; bf0[5] = c0; bf0[6] = c0; bf0[7] = c0;
        bf1[0] = (_Float16)x1 * cm2; bf1[1] = (_Float16)y1 * cm2; bf1[2] = (_Float16)z1 * cm2;
        bf1[3] = c1; bf1[4] = c0; bf1[5] = c0; bf1[6] = c0; bf1[7] = c0;
        if (lane >= 32) {
            #pragma unroll
            for (int j = 0; j < 8; ++j) { bf0[j] = c0; bf1[j] = c0; }
        }
    }

    f32x16 cz;
    float rm0[8], rm1[8];
    #pragma unroll
    for (int j = 0; j < 16; ++j) cz[j] = 0.f;
    #pragma unroll
    for (int j = 0; j < 8; ++j) { rm0[j] = FLT_MAX; rm1[j] = FLT_MAX; }

    // 4 bodies (128 targets) per iteration, depth-4 raw-coord prefetch.
    const int NIT = N >> 9;                        // (N/4)/128
    const float* tp = T + (size_t)(wave * (N >> 2) + ((lane < 32) ? col : 0)) * 3;

    float x0r = tp[0],   y0r = tp[1],   z0r = tp[2];
    float x1r = tp[96],  y1r = tp[97],  z1r = tp[98];
    float x2r = tp[192], y2r = tp[193], z2r = tp[194];
    float x3r = tp[288], y3r = tp[289], z3r = tp[290];

#define CORE_T(X, Y, Z)                                                 \
    {                                                                   \
        _Float16 hx = (_Float16)(X), hy = (_Float16)(Y), hz = (_Float16)(Z); \
        float tn = (X)*(X) + (Y)*(Y) + (Z)*(Z);                         \
        f16x8 a;                                                        \
        a[0] = hx; a[1] = hy; a[2] = hz; a[3] = (_Float16)tn;           \
        a[4] = (_Float16)0.f; a[5] = (_Float16)0.f;                     \
        a[6] = (_Float16)0.f; a[7] = (_Float16)0.f;                     \
        f32x16 r0 = MFMA16(a, bf0, cz);                                 \
        f32x16 r1 = MFMA16(a, bf1, cz);                                 \
        _Pragma("unroll")                                               \
        for (int j = 0; j < 8; ++j) {                                   \
            rm0[j] = fminf(fminf(r0[2*j], r0[2*j+1]), rm0[j]);          \
            rm1[j] = fminf(fminf(r1[2*j], r1[2*j+1]), rm1[j]);          \
        }                                                               \
    }
#define BODY_T(X, Y, Z, OFF)                                            \
    CORE_T(X, Y, Z)                                                     \
    X = tp[OFF]; Y = tp[OFF + 1]; Z = tp[OFF + 2];

    for (int it = 0; it < NIT - 1; ++it) {
        BODY_T(x0r, y0r, z0r, 384)
        BODY_T(x1r, y1r, z1r, 480)
        BODY_T(x2r, y2r, z2r, 576)
        BODY_T(x3r, y3r, z3r, 672)
        tp += 384;
    }
    CORE_T(x0r, y0r, z0r)
    CORE_T(x1r, y1r, z1r)
    CORE_T(x2r, y2r, z2r)
    CORE_T(x3r, y3r, z3r)
#undef BODY_T
#undef CORE_T

    float m0 = rm0[0], m1 = rm1[0];
    #pragma unroll
    for (int j = 1; j < 8; ++j) { m0 = fminf(m0, rm0[j]); m1 = fminf(m1, rm1[j]); }
    return make_float2(m0, m1);
}

// ---------------- single-dispatch cooperative kernel ----------------
__global__ __launch_bounds__(BLK, 4) void chamfer_coop(
    const float* __restrict__ preds, const float* __restrict__ gts,
    float* __restrict__ partials, float* __restrict__ out,
    int N, int out_size) {

    const int dir  = blockIdx.z;
    const int b    = blockIdx.y;
    const int tid  = threadIdx.x;
    const int wave = tid >> 6;
    const int lane = tid & 63;
    const int qb   = blockIdx.x * 64;

    const float* Q = ((dir == 0) ? preds : gts) + (size_t)b * N * 3;
    const float* T = ((dir == 0) ? gts   : preds) + (size_t)b * N * 3;

    float2 mm = chamfer_tile(Q, T, N, wave, lane, qb);

    __shared__ float lds[4][2][64];
    lds[wave][0][lane] = mm.x;
    lds[wave][1][lane] = mm.y;
    __syncthreads();

    if (tid < 64) {
        int s = tid >> 5, c = tid & 31;
        float m = FLT_MAX;
        #pragma unroll
        for (int w = 0; w < 4; ++w)
            m = fminf(m, fminf(lds[w][s][c], lds[w][s][c + 32]));
        int q = qb + s * 32 + c;
        float x = Q[q*3], y = Q[q*3+1], z = Q[q*3+2];
        float xr = (float)(_Float16)x, yr = (float)(_Float16)y, zr = (float)(_Float16)z;
        float val = m + (xr * xr + yr * yr + zr * zr);
        #pragma unroll
        for (int off = 32; off > 0; off >>= 1)
            val += __shfl_down(val, off, 64);
        if (tid == 0) {
            int flat = blockIdx.x + gridDim.x * (blockIdx.y + 4 * blockIdx.z);
            partials[flat] = val;
        }
    }
    __threadfence();
    cg::this_grid().sync();

    if (blockIdx.x == 0 && blockIdx.y == 0 && blockIdx.z == 0) {
        int nb = gridDim.x * gridDim.y * gridDim.z;
        float s = 0.f;
        for (int i = tid; i < nb; i += BLK) s += partials[i];
        __shared__ float psum[BLK / 64];
        #pragma unroll
        for (int off = 32; off > 0; off >>= 1) s += __shfl_down(s, off, 64);
        if ((tid & 63) == 0) psum[tid >> 6] = s;
        __syncthreads();
        if (tid == 0) {
            float t = 0.f;
            #pragma unroll
            for (int w = 0; w < BLK / 64; ++w) t += psum[w];
            out[0] = t;
        }
        for (int i = 1 + tid; i < out_size; i += BLK) out[i] = 0.f;
    }
}

// ---------------- fallback: two-dispatch path ----------------
__global__ __launch_bounds__(BLK, 2) void chamfer_mfma(
    const float* __restrict__ preds, const float* __restrict__ gts,
    float* __restrict__ partials, int N) {

    const int dir  = blockIdx.z;
    const int b    = blockIdx.y;
    const int tid  = threadIdx.x;
    const int wave = tid >> 6;
    const int lane = tid & 63;
    const int qb   = blockIdx.x * 64;

    const float* Q = ((dir == 0) ? preds : gts) + (size_t)b * N * 3;
    const float* T = ((dir == 0) ? gts   : preds) + (size_t)b * N * 3;

    float2 mm = chamfer_tile(Q, T, N, wave, lane, qb);

    __shared__ float lds[4][2][64];
    lds[wave][0][lane] = mm.x;
    lds[wave][1][lane] = mm.y;
    __syncthreads();

    if (tid < 64) {
        int s = tid >> 5, c = tid & 31;
        float m = FLT_MAX;
        #pragma unroll
        for (int w = 0; w < 4; ++w)
            m = fminf(m, fminf(lds[w][s][c], lds[w][s][c + 32]));
        int q = qb + s * 32 + c;
        float x = Q[q*3], y = Q[q*3+1], z = Q[q*3+2];
        float xr = (float)(_Float16)x, yr = (float)(_Float16)y, zr = (float)(_Float16)z;
        float val = m + (xr * xr + yr * yr + zr * zr);
        #pragma unroll
        for (int off = 32; off > 0; off >>= 1)
            val += __shfl_down(val, off, 64);
        if (tid == 0) {
            int flat = blockIdx.x + gridDim.x * (blockIdx.y + 4 * blockIdx.z);
            partials[flat] = val;
        }
    }
}

__global__ __launch_bounds__(BLK) void chamfer_reduce(
    const float* __restrict__ partials, float* __restrict__ out,
    int nparts, int out_size) {
    const int tid = threadIdx.x;
    float s = 0.f;
    for (int i = tid; i < nparts; i += BLK) s += partials[i];
    __shared__ float psum[BLK / 64];
    #pragma unroll
    for (int off = 32; off > 0; off >>= 1) s += __shfl_down(s, off, 64);
    if ((tid & 63) == 0) psum[tid >> 6] = s;
    __syncthreads();
    if (tid == 0) {
        float t = 0.f;
        #pragma unroll
        for (int w = 0; w < BLK / 64; ++w) t += psum[w];
        out[0] = t;
    }
    for (int i = 1 + tid; i < out_size; i += BLK) out[i] = 0.f;
}

// ---------------- last-resort fallback (R5 VALU version) ----------------
#define SEG  32
#define Q    8

__device__ __forceinline__ float min3f(float a, float b, float c) {
    float r;
    asm("v_min3_f32 %0, %1, %2, %3" : "=v"(r) : "v"(a), "v"(b), "v"(c));
    return r;
}
__device__ __forceinline__ f32x2 pk_fma(f32x2 a, f32x2 b, f32x2 c) {
    f32x2 d;
    asm("v_pk_fma_f32 %0, %1, %2, %3" : "=v"(d) : "v"(a), "v"(b), "v"(c));
    return d;
}
__device__ __forceinline__ f32x2 pk_mul(f32x2 a, f32x2 b) {
    f32x2 d;
    asm("v_pk_mul_f32 %0, %1, %2" : "=v"(d) : "v"(a), "v"(b));
    return d;
}

__global__ __launch_bounds__(BLK, 4) void chamfer_min_kernel(
    const float* __restrict__ preds, const float* __restrict__ gts,
    unsigned int* __restrict__ keys, int N) {
    const int seg = blockIdx.z % SEG;
    const int dir = blockIdx.z / SEG;
    const int b   = blockIdx.y;
    const int tid = threadIdx.x;
    const int TT  = N / SEG;
    const float* Aq = dir == 0 ? preds : gts;
    const float* Bt = dir == 0 ? gts   : preds;
    const float* Ab = Aq + (size_t)b * N * 3;
    const float* Bb = Bt + (size_t)b * N * 3;
    __shared__ f32x2 shx[256], shy[256], shz[256];
    const int qbase = blockIdx.x * (BLK * Q);
    f32x2 a2x[Q], a2y[Q], a2z[Q];
    float an[Q]; bool vq[Q];
    #pragma unroll
    for (int q = 0; q < Q; ++q) {
        int idx = qbase + q * BLK + tid;
        vq[q] = idx < N;
        int ci = vq[q] ? idx : 0;
        float ax = Ab[ci*3], ay = Ab[ci*3+1], az = Ab[ci*3+2];
        a2x[q] = f32x2{-2.f*ax, -2.f*ax};
        a2y[q] = f32x2{-2.f*ay, -2.f*ay};
        a2z[q] = f32x2{-2.f*az, -2.f*az};
        an[q]  = ax*ax + ay*ay + az*az;
    }
    for (int p = tid; p < (TT >> 1); p += BLK) {
        int j0 = seg * TT + 2 * p;
        const f32x2* src = (const f32x2*)(Bb + (size_t)j0 * 3);
        f32x2 v01 = src[0], v23 = src[1], v45 = src[2];
        shx[p] = f32x2{v01.x, v23.y};
        shy[p] = f32x2{v01.y, v45.x};
        shz[p] = f32x2{v23.x, v45.y};
    }
    __syncthreads();
    float m[Q];
    #pragma unroll
    for (int q = 0; q < Q; ++q) m[q] = FLT_MAX;
    const f32x4* X4 = (const f32x4*)shx;
    const f32x4* Y4 = (const f32x4*)shy;
    const f32x4* Z4 = (const f32x4*)shz;
    const int KITER = TT >> 2;
    #pragma unroll 2
    for (int k = 0; k < KITER; ++k) {
        f32x4 X = X4[k], Y = Y4[k], Z = Z4[k];
        f32x2 w01 = pk_fma(Z.lo, Z.lo, pk_fma(Y.lo, Y.lo, pk_mul(X.lo, X.lo)));
        f32x2 w23 = pk_fma(Z.hi, Z.hi, pk_fma(Y.hi, Y.hi, pk_mul(X.hi, X.hi)));
        #pragma unroll
        for (int q = 0; q < Q; ++q) {
            f32x2 d0 = pk_fma(a2x[q], X.lo, pk_fma(a2y[q], Y.lo, pk_fma(a2z[q], Z.lo, w01)));
            f32x2 d1 = pk_fma(a2x[q], X.hi, pk_fma(a2y[q], Y.hi, pk_fma(a2z[q], Z.hi, w23)));
            m[q] = min3f(d0.x, d0.y, m[q]);
            m[q] = min3f(d1.x, d1.y, m[q]);
        }
    }
    #pragma unroll
    for (int q = 0; q < Q; ++q) {
        if (vq[q]) {
            int idx = qbase + q * BLK + tid;
            atomicMin(keys + ((size_t)(dir*4 + b) * N + idx), enc_f32(m[q] + an[q]));
        }
    }
}

__global__ __launch_bounds__(BLK) void chamfer_sum_kernel(
    const unsigned int* __restrict__ keys, float* __restrict__ out, int M) {
    __shared__ float psum[BLK / 64];
    int gid = blockIdx.x * BLK + threadIdx.x;
    int stride = gridDim.x * BLK;
    float s = 0.f;
    for (int i = gid; i < M; i += stride) s += dec_f32(keys[i]);
    for (int off = 32; off > 0; off >>= 1) s += __shfl_down(s, off, 64);
    if ((threadIdx.x & 63) == 0) psum[threadIdx.x >> 6] = s;
    __syncthreads();
    if (threadIdx.x == 0) {
        float t = 0.f;
        for (int w = 0; w < BLK / 64; ++w) t += psum[w];
        atomicAdd(out, t);
    }
}

extern "C" void kernel_launch(void* const* d_in, const int* in_sizes, int n_in,
                              void* d_out, int out_size, void* d_ws, size_t ws_size,
                              hipStream_t stream) {
    const float* preds = (const float*)d_in[0];
    const float* gts   = (const float*)d_in[1];
    float* out = (float*)d_out;

    const int B = 4, D = 3;
    const int N = in_sizes[0] / (B * D);   // 8192

    const int    nb   = (N / 64) * B * 2;  // 1024
    const size_t need = (size_t)nb * sizeof(float);

    if (ws_size >= need && (N % 1024) == 0) {
        float* partials = (float*)d_ws;
        dim3 grid(N / 64, B, 2);

        bool launched = false;
        int occ = 0;
        hipError_t qrc = hipOccupancyMaxActiveBlocksPerMultiprocessor(
            &occ, reinterpret_cast<const void*>(chamfer_coop), BLK, 0);
        long long total_blocks = (long long)grid.x * grid.y * grid.z;
        if (qrc == hipSuccess && (long long)occ * 256 >= total_blocks) {
            int n_local = N, osz_local = out_size;
            void* args[] = {(void*)&preds, (void*)&gts, (void*)&partials,
                            (void*)&out, (void*)&n_local, (void*)&osz_local};
            hipError_t rc = hipLaunchCooperativeKernel(
                reinterpret_cast<const void*>(chamfer_coop),
                grid, dim3(BLK), args, 0, stream);
            launched = (rc == hipSuccess);
        }
        if (!launched) {
            chamfer_mfma<<<grid, BLK, 0, stream>>>(preds, gts, partials, N);
            chamfer_reduce<<<1, BLK, 0, stream>>>(partials, out, nb, out_size);
        }
    } else {
        hipMemsetAsync(out, 0, sizeof(float) * out_size, stream);
        const size_t keys_bytes = (size_t)2 * B * N * sizeof(unsigned int);
        unsigned int* keys = (unsigned int*)d_ws;
        hipMemsetAsync(keys, 0xFF, keys_bytes, stream);
        dim3 grid((N + BLK * Q - 1) / (BLK * Q), B, 2 * SEG);
        chamfer_min_kernel<<<grid, BLK, 0, stream>>>(preds, gts, keys, N);
        chamfer_sum_kernel<<<64, BLK, 0, stream>>>(keys, out, 2 * B * N);
    }
}